// Round 1
// baseline (62495.746 us; speedup 1.0000x reference)
//
#include <hip/hip_runtime.h>

#define B_ 16
#define S_ 1024
#define H_ 512
#define E_ 512
#define L_ 10

__device__ __forceinline__ float sigmoidf_(float x) { return 1.0f / (1.0f + expf(-x)); }

// ---------------------------------------------------------------- embedding
__global__ __launch_bounds__(128) void embed_kernel(const int* __restrict__ tokens,
                                                    const float* __restrict__ emb,
                                                    float* __restrict__ x0)
{
    const int row = blockIdx.x;              // b*S + s
    const int tok = tokens[row];
    const float4* src = (const float4*)(emb + (size_t)tok * E_);
    float4* dst = (float4*)(x0 + (size_t)row * E_);
    dst[threadIdx.x] = src[threadIdx.x];
}

// ---------------------------------------------------------------- bidirectional LSTM layer
// Persistent kernel: 256 blocks (1 per CU). dir = bid>>7; block owns 4 cells
// (c0..c0+3) => 16 gate rows (4 gates x 4 cells). W_ih/W_hh rows live in LDS.
// Per step: x-part GEMM (no recurrent dep, hides sync), flag-wait for h(t-1),
// h-part GEMM, reduce, cell update, publish h via agent-scope stores.
template<int DIN>
__global__ __launch_bounds__(256) void lstm_bidir(
    const float* __restrict__ x,
    const float* __restrict__ wihF, const float* __restrict__ whhF,
    const float* __restrict__ bihF, const float* __restrict__ bhhF,
    const float* __restrict__ wihR, const float* __restrict__ whhR,
    const float* __restrict__ bihR, const float* __restrict__ bhhR,
    float* __restrict__ hs,          // (B, S, 1024): [0:512]=fwd, [512:1024]=rev
    int* __restrict__ flags)         // 256 flags, stride 32 ints
{
    const int tid = threadIdx.x;
    const int bid = blockIdx.x;
    const int dir = bid >> 7;
    const int sub = bid & 127;
    const int c0  = sub << 2;

    const float* wih = dir ? wihR : wihF;
    const float* whh = dir ? whhR : whhF;
    const float* bih = dir ? bihR : bihF;
    const float* bhh = dir ? bhhR : bhhF;

    __shared__ float s_wih[16][DIN + 4];
    __shared__ float s_whh[16][H_ + 4];
    __shared__ float s_stage[16][H_ + 4];
    __shared__ float s_red[4][16][16];
    __shared__ float s_gl[16][17];
    __shared__ float s_bias[16];

    // ---- load weight rows into LDS (once)
    for (int r = 0; r < 16; ++r) {
        const int grow = ((r >> 2) * H_) + c0 + (r & 3);
        const float* srcI = wih + (size_t)grow * DIN;
        for (int i = tid; i < DIN / 4; i += 256)
            *(float4*)&s_wih[r][i * 4] = *(const float4*)&srcI[i * 4];
        const float* srcH = whh + (size_t)grow * H_;
        for (int i = tid; i < H_ / 4; i += 256)
            *(float4*)&s_whh[r][i * 4] = *(const float4*)&srcH[i * 4];
    }
    if (tid < 16) {
        const int grow = ((tid >> 2) * H_) + c0 + (tid & 3);
        s_bias[tid] = bih[grow] + bhh[grow];
    }

    // thread decomposition: tid = ks*16 + (r4*4 + b4)
    const int rb  = tid & 15;
    const int ks  = tid >> 4;
    const int r40 = (rb >> 2) << 2;
    const int b40 = (rb & 3) << 2;
    const int kb  = ks << 5;

    float cstate = 0.0f;                 // meaningful for tid<64
    const int cu_c = tid >> 4;           // cell offset (tid<64)
    const int cu_b = tid & 15;           // batch      (tid<64)

    __syncthreads();

    for (int step = 0; step < S_; ++step) {
        const int t = dir ? (S_ - 1 - step) : step;
        float acc[16];
        #pragma unroll
        for (int a = 0; a < 16; ++a) acc[a] = 0.0f;

        // -------- x part: gates += x_t @ W_ih^T  (no dependency on h)
        #pragma unroll
        for (int half = 0; half < DIN / 512; ++half) {
            __syncthreads();
            for (int i = tid; i < 2048; i += 256) {
                const int bb = i >> 7;
                const int col = (i & 127) << 2;
                *(float4*)&s_stage[bb][col] =
                    *(const float4*)&x[(size_t)(bb * S_ + t) * DIN + half * 512 + col];
            }
            __syncthreads();
            #pragma unroll
            for (int cc = 0; cc < 8; ++cc) {
                const int rot  = ((cc + ks) & 7) << 2;   // bank-conflict rotation
                const int scol = kb + rot;
                const int wcol = half * 512 + scol;
                float4 hv[4], wv[4];
                #pragma unroll
                for (int i = 0; i < 4; ++i) hv[i] = *(const float4*)&s_stage[b40 + i][scol];
                #pragma unroll
                for (int j = 0; j < 4; ++j) wv[j] = *(const float4*)&s_wih[r40 + j][wcol];
                #pragma unroll
                for (int j = 0; j < 4; ++j)
                    #pragma unroll
                    for (int i = 0; i < 4; ++i) {
                        acc[j * 4 + i] = fmaf(wv[j].x, hv[i].x, acc[j * 4 + i]);
                        acc[j * 4 + i] = fmaf(wv[j].y, hv[i].y, acc[j * 4 + i]);
                        acc[j * 4 + i] = fmaf(wv[j].z, hv[i].z, acc[j * 4 + i]);
                        acc[j * 4 + i] = fmaf(wv[j].w, hv[i].w, acc[j * 4 + i]);
                    }
            }
        }

        // -------- wait for h(t-1), then h part: gates += h @ W_hh^T
        if (step > 0) {
            if (tid < 128) {
                int* fp = &flags[(dir * 128 + tid) << 5];
                while (__hip_atomic_load(fp, __ATOMIC_RELAXED, __HIP_MEMORY_SCOPE_AGENT) < step) { }
            }
            __syncthreads();
            __builtin_amdgcn_fence(__ATOMIC_ACQUIRE, "agent");
            const int tp = dir ? (t + 1) : (t - 1);
            for (int i = tid; i < 2048; i += 256) {
                const int bb = i >> 7;
                const int col = (i & 127) << 2;
                *(float4*)&s_stage[bb][col] =
                    *(const float4*)&hs[(size_t)(bb * S_ + tp) * 1024 + dir * 512 + col];
            }
            __syncthreads();
            #pragma unroll
            for (int cc = 0; cc < 8; ++cc) {
                const int rot  = ((cc + ks) & 7) << 2;
                const int scol = kb + rot;
                float4 hv[4], wv[4];
                #pragma unroll
                for (int i = 0; i < 4; ++i) hv[i] = *(const float4*)&s_stage[b40 + i][scol];
                #pragma unroll
                for (int j = 0; j < 4; ++j) wv[j] = *(const float4*)&s_whh[r40 + j][scol];
                #pragma unroll
                for (int j = 0; j < 4; ++j)
                    #pragma unroll
                    for (int i = 0; i < 4; ++i) {
                        acc[j * 4 + i] = fmaf(wv[j].x, hv[i].x, acc[j * 4 + i]);
                        acc[j * 4 + i] = fmaf(wv[j].y, hv[i].y, acc[j * 4 + i]);
                        acc[j * 4 + i] = fmaf(wv[j].z, hv[i].z, acc[j * 4 + i]);
                        acc[j * 4 + i] = fmaf(wv[j].w, hv[i].w, acc[j * 4 + i]);
                    }
            }
        }

        // -------- reduce partial sums over the 16 k-slices
        #pragma unroll
        for (int a = 0; a < 16; ++a) {
            float v = acc[a];
            v += __shfl_xor(v, 16);
            v += __shfl_xor(v, 32);
            acc[a] = v;
        }
        if ((tid & 63) < 16) {
            const int w = tid >> 6;
            #pragma unroll
            for (int a = 0; a < 16; ++a) s_red[w][tid & 15][a] = acc[a];
        }
        __syncthreads();
        {
            const int r  = tid >> 4;     // local gate row 0..15
            const int bb = tid & 15;     // batch
            const int rr = ((r >> 2) << 2) + (bb >> 2);
            const int aa = ((r & 3) << 2) + (bb & 3);
            float g = s_bias[r];
            #pragma unroll
            for (int w = 0; w < 4; ++w) g += s_red[w][rr][aa];
            s_gl[r][bb] = g;
        }
        __syncthreads();

        // -------- cell update (4 cells x 16 batches = 64 threads)
        if (tid < 64) {
            const float gi = s_gl[0  + cu_c][cu_b];
            const float gf = s_gl[4  + cu_c][cu_b];
            const float gg = s_gl[8  + cu_c][cu_b];
            const float go = s_gl[12 + cu_c][cu_b];
            const float iv = sigmoidf_(gi);
            const float fv = sigmoidf_(gf);
            const float gv = tanhf(gg);
            const float ov = sigmoidf_(go);
            cstate = fv * cstate + iv * gv;
            const float hval = ov * tanhf(cstate);
            __hip_atomic_store(&hs[(size_t)(cu_b * S_ + t) * 1024 + dir * 512 + c0 + cu_c],
                               hval, __ATOMIC_RELAXED, __HIP_MEMORY_SCOPE_AGENT);
        }
        __threadfence();         // drain h stores to device scope
        __syncthreads();
        if (tid == 0)
            __hip_atomic_store(&flags[bid << 5], step + 1,
                               __ATOMIC_RELEASE, __HIP_MEMORY_SCOPE_AGENT);
    }
}

// ---------------------------------------------------------------- out proj + argmax -> mask
__global__ __launch_bounds__(256) void outproj_kernel(
    const float* __restrict__ x1, const float* __restrict__ out_w,
    const float* __restrict__ out_b, float* __restrict__ res,
    unsigned char* __restrict__ mask)
{
    const int tid  = threadIdx.x;
    const int lane = tid & 63;
    const int w    = tid >> 6;
    const int row  = blockIdx.x * 4 + w;     // b*S + s
    const float* xr = x1 + (size_t)row * 1024;
    float4 xv[4];
    #pragma unroll
    for (int i = 0; i < 4; ++i) xv[i] = *(const float4*)&xr[(i * 64 + lane) << 2];
    float best = -__builtin_inff();
    int bi = 0;
    #pragma unroll
    for (int l = 0; l < L_; ++l) {
        const float* wr = out_w + l * 1024;
        float s = 0.0f;
        #pragma unroll
        for (int i = 0; i < 4; ++i) {
            const float4 wv = *(const float4*)&wr[(i * 64 + lane) << 2];
            s = fmaf(xv[i].x, wv.x, s);
            s = fmaf(xv[i].y, wv.y, s);
            s = fmaf(xv[i].z, wv.z, s);
            s = fmaf(xv[i].w, wv.w, s);
        }
        #pragma unroll
        for (int d = 32; d >= 1; d >>= 1) s += __shfl_xor(s, d);
        s += out_b[l];
        if (lane == l) res[(size_t)row * L_ + l] = s;
        if (s > best) { best = s; bi = l; }     // strict > keeps first index (jnp.argmax)
    }
    if (lane == 0) mask[row] = (unsigned char)(bi != 0);
}

// ---------------------------------------------------------------- batched fp32 GEMM 64x64x16
// MODE 0: C = A @ B^T        (A:(M,K), B:(N,K))      -> scores
// MODE 1: C = A @ B + D      (A:(M,K), B:(K,N))      -> A-out with residual
template<int MODE>
__global__ __launch_bounds__(256) void gemm64(
    const float* __restrict__ A, const float* __restrict__ Bm,
    const float* __restrict__ D, float* __restrict__ C,
    const int M, const int N, const int K)
{
    const int bz = blockIdx.z;
    const float* Ab = A  + (size_t)bz * M * K;
    const float* Bb = Bm + (size_t)bz * N * K;
    const float* Db = (MODE == 1) ? (D + (size_t)bz * M * N) : (const float*)nullptr;
    float* Cb = C + (size_t)bz * M * N;
    const int m0 = blockIdx.y << 6;
    const int n0 = blockIdx.x << 6;
    const int tid = threadIdx.x;
    const int tm = tid >> 4, tn = tid & 15;
    const int am = tid >> 2, ak = (tid & 3) << 2;
    const int bk1 = tid >> 4, bn1 = (tid & 15) << 2;
    __shared__ float As[16][68];
    __shared__ float Bs[16][68];
    float acc[4][4] = {};
    for (int k0 = 0; k0 < K; k0 += 16) {
        const float4 av = *(const float4*)&Ab[(size_t)(m0 + am) * K + k0 + ak];
        float4 bv;
        if (MODE == 0) bv = *(const float4*)&Bb[(size_t)(n0 + am) * K + k0 + ak];
        else           bv = *(const float4*)&Bb[(size_t)(k0 + bk1) * N + n0 + bn1];
        __syncthreads();
        As[ak + 0][am] = av.x; As[ak + 1][am] = av.y;
        As[ak + 2][am] = av.z; As[ak + 3][am] = av.w;
        if (MODE == 0) {
            Bs[ak + 0][am] = bv.x; Bs[ak + 1][am] = bv.y;
            Bs[ak + 2][am] = bv.z; Bs[ak + 3][am] = bv.w;
        } else {
            *(float4*)&Bs[bk1][bn1] = bv;
        }
        __syncthreads();
        #pragma unroll
        for (int k = 0; k < 16; ++k) {
            const float4 a4 = *(const float4*)&As[k][tm << 2];
            const float4 b4 = *(const float4*)&Bs[k][tn << 2];
            acc[0][0] = fmaf(a4.x, b4.x, acc[0][0]); acc[0][1] = fmaf(a4.x, b4.y, acc[0][1]);
            acc[0][2] = fmaf(a4.x, b4.z, acc[0][2]); acc[0][3] = fmaf(a4.x, b4.w, acc[0][3]);
            acc[1][0] = fmaf(a4.y, b4.x, acc[1][0]); acc[1][1] = fmaf(a4.y, b4.y, acc[1][1]);
            acc[1][2] = fmaf(a4.y, b4.z, acc[1][2]); acc[1][3] = fmaf(a4.y, b4.w, acc[1][3]);
            acc[2][0] = fmaf(a4.z, b4.x, acc[2][0]); acc[2][1] = fmaf(a4.z, b4.y, acc[2][1]);
            acc[2][2] = fmaf(a4.z, b4.z, acc[2][2]); acc[2][3] = fmaf(a4.z, b4.w, acc[2][3]);
            acc[3][0] = fmaf(a4.w, b4.x, acc[3][0]); acc[3][1] = fmaf(a4.w, b4.y, acc[3][1]);
            acc[3][2] = fmaf(a4.w, b4.z, acc[3][2]); acc[3][3] = fmaf(a4.w, b4.w, acc[3][3]);
        }
    }
    #pragma unroll
    for (int j = 0; j < 4; ++j) {
        const size_t ci = (size_t)(m0 + (tm << 2) + j) * N + n0 + (tn << 2);
        float4 o = make_float4(acc[j][0], acc[j][1], acc[j][2], acc[j][3]);
        if (MODE == 1) {
            const float4 dv = *(const float4*)&Db[ci];
            o.x += dv.x; o.y += dv.y; o.z += dv.z; o.w += dv.w;
        }
        *(float4*)&Cb[ci] = o;
    }
}

// ---------------------------------------------------------------- dual masked softmax (in place)
__global__ __launch_bounds__(256) void softmax_kernel(float* __restrict__ sc,
                                                      const unsigned char* __restrict__ mask)
{
    const float INF = __builtin_inff();
    const int row = blockIdx.x;          // b*S + s
    const int b = row >> 10;
    float* pr = sc + (size_t)row * 1024;
    const unsigned char* mr = mask + b * 1024;
    const int tid = threadIdx.x;
    const int lane = tid & 63;
    const int w = tid >> 6;
    const int j0 = tid << 2;
    const float4 v = *(const float4*)&pr[j0];
    const unsigned mu = *(const unsigned*)&mr[j0];
    const bool m0 = (mu & 0xffu) != 0, m1 = ((mu >> 8) & 0xffu) != 0;
    const bool m2 = ((mu >> 16) & 0xffu) != 0, m3 = ((mu >> 24) & 0xffu) != 0;

    float mme = -INF, mot = -INF;
    if (m0) mme = fmaxf(mme, v.x); else mot = fmaxf(mot, v.x);
    if (m1) mme = fmaxf(mme, v.y); else mot = fmaxf(mot, v.y);
    if (m2) mme = fmaxf(mme, v.z); else mot = fmaxf(mot, v.z);
    if (m3) mme = fmaxf(mme, v.w); else mot = fmaxf(mot, v.w);
    #pragma unroll
    for (int d = 32; d >= 1; d >>= 1) {
        mme = fmaxf(mme, __shfl_xor(mme, d));
        mot = fmaxf(mot, __shfl_xor(mot, d));
    }
    __shared__ float sm[2][4];
    if (lane == 0) { sm[0][w] = mme; sm[1][w] = mot; }
    __syncthreads();
    float Mme = fmaxf(fmaxf(sm[0][0], sm[0][1]), fmaxf(sm[0][2], sm[0][3]));
    float Mot = fmaxf(fmaxf(sm[1][0], sm[1][1]), fmaxf(sm[1][2], sm[1][3]));
    const float MmeU = (Mme == -INF) ? 0.0f : Mme;
    const float MotU = (Mot == -INF) ? 0.0f : Mot;

    const float e0 = expf(v.x - (m0 ? MmeU : MotU));
    const float e1 = expf(v.y - (m1 ? MmeU : MotU));
    const float e2 = expf(v.z - (m2 ? MmeU : MotU));
    const float e3 = expf(v.w - (m3 ? MmeU : MotU));
    float sme = 0.0f, sot = 0.0f;
    if (m0) sme += e0; else sot += e0;
    if (m1) sme += e1; else sot += e1;
    if (m2) sme += e2; else sot += e2;
    if (m3) sme += e3; else sot += e3;
    #pragma unroll
    for (int d = 32; d >= 1; d >>= 1) {
        sme += __shfl_xor(sme, d);
        sot += __shfl_xor(sot, d);
    }
    __syncthreads();
    if (lane == 0) { sm[0][w] = sme; sm[1][w] = sot; }
    __syncthreads();
    const float Dme = sm[0][0] + sm[0][1] + sm[0][2] + sm[0][3];
    const float Dot = sm[1][0] + sm[1][1] + sm[1][2] + sm[1][3];

    float4 o;
    o.x = m0 ? (Dme > 0.0f ? e0 / Dme : 0.0f) : (Dot > 0.0f ? e0 / Dot : 0.0f);
    o.y = m1 ? (Dme > 0.0f ? e1 / Dme : 0.0f) : (Dot > 0.0f ? e1 / Dot : 0.0f);
    o.z = m2 ? (Dme > 0.0f ? e2 / Dme : 0.0f) : (Dot > 0.0f ? e2 / Dot : 0.0f);
    o.w = m3 ? (Dme > 0.0f ? e3 / Dme : 0.0f) : (Dot > 0.0f ? e3 / Dot : 0.0f);
    *(float4*)&pr[j0] = o;
}

// ---------------------------------------------------------------- launch
extern "C" void kernel_launch(void* const* d_in, const int* in_sizes, int n_in,
                              void* d_out, int out_size, void* d_ws, size_t ws_size,
                              hipStream_t stream)
{
    const float* emb     = (const float*)d_in[0];
    const float* wih_l0  = (const float*)d_in[1];
    const float* whh_l0  = (const float*)d_in[2];
    const float* bih_l0  = (const float*)d_in[3];
    const float* bhh_l0  = (const float*)d_in[4];
    const float* wih_l0r = (const float*)d_in[5];
    const float* whh_l0r = (const float*)d_in[6];
    const float* bih_l0r = (const float*)d_in[7];
    const float* bhh_l0r = (const float*)d_in[8];
    const float* wih_l1  = (const float*)d_in[9];
    const float* whh_l1  = (const float*)d_in[10];
    const float* bih_l1  = (const float*)d_in[11];
    const float* bhh_l1  = (const float*)d_in[12];
    const float* wih_l1r = (const float*)d_in[13];
    const float* whh_l1r = (const float*)d_in[14];
    const float* bih_l1r = (const float*)d_in[15];
    const float* bhh_l1r = (const float*)d_in[16];
    const float* out_w   = (const float*)d_in[17];
    const float* out_b   = (const float*)d_in[18];
    const int*   tokens  = (const int*)d_in[19];

    float* out     = (float*)d_out;
    float* A_out   = out;                          // (16,1024,1024)
    float* res_out = out + 16777216;               // (16,1024,10)

    float* ws = (float*)d_ws;
    float* x0 = ws;                                //  8,388,608 f
    float* h0 = ws + 8388608;                      // 16,777,216 f
    float* x1 = h0 + 16777216;                     // 16,777,216 f
    float* sc = x1 + 16777216;                     // 16,777,216 f (scores, then P in place)
    unsigned char* mask = (unsigned char*)(sc + 16777216);   // 16,384 B
    int* flags0 = (int*)(mask + 16384);            // 256*32 ints
    int* flags1 = flags0 + 256 * 32;

    (void)in_sizes; (void)n_in; (void)out_size; (void)ws_size;

    hipMemsetAsync(flags0, 0, 2 * 256 * 32 * sizeof(int), stream);

    embed_kernel<<<B_ * S_, 128, 0, stream>>>(tokens, emb, x0);

    lstm_bidir<512><<<256, 256, 0, stream>>>(
        x0, wih_l0, whh_l0, bih_l0, bhh_l0,
        wih_l0r, whh_l0r, bih_l0r, bhh_l0r, h0, flags0);

    lstm_bidir<1024><<<256, 256, 0, stream>>>(
        h0, wih_l1, whh_l1, bih_l1, bhh_l1,
        wih_l1r, whh_l1r, bih_l1r, bhh_l1r, x1, flags1);

    outproj_kernel<<<(B_ * S_) / 4, 256, 0, stream>>>(x1, out_w, out_b, res_out, mask);

    dim3 gg(16, 16, 16);
    gemm64<0><<<gg, 256, 0, stream>>>(x1, x1, nullptr, sc, 1024, 1024, 1024);

    softmax_kernel<<<B_ * S_, 256, 0, stream>>>(sc, mask);

    gemm64<1><<<gg, 256, 0, stream>>>(sc, x1, x1, A_out, 1024, 1024, 1024);
}

// Round 3
// 16881.427 us; speedup vs baseline: 3.7020x; 3.7020x over previous
//
#include <hip/hip_runtime.h>

#define B_ 16
#define S_ 1024
#define H_ 512
#define E_ 512
#define L_ 10

typedef float f4_t __attribute__((ext_vector_type(4)));

__device__ __forceinline__ float sigmoidf_(float x) { return 1.0f / (1.0f + expf(-x)); }

// Write-through store: bypasses L1/L2 (sc0 sc1), visible at LLC (coherence
// point) once acked (vmcnt). ext_vector_type binds to a VGPR quad (HIP's
// float4 struct cannot — "indirect register inputs" compile error).
__device__ __forceinline__ void store_wt4(float* p, f4_t v)
{
    asm volatile("global_store_dwordx4 %0, %1, off sc0 sc1" :: "v"(p), "v"(v) : "memory");
}

// ---------------------------------------------------------------- embedding
__global__ __launch_bounds__(128) void embed_kernel(const int* __restrict__ tokens,
                                                    const float* __restrict__ emb,
                                                    float* __restrict__ x0)
{
    const int row = blockIdx.x;              // b*S + s
    const int tok = tokens[row];
    const float4* src = (const float4*)(emb + (size_t)tok * E_);
    float4* dst = (float4*)(x0 + (size_t)row * E_);
    dst[threadIdx.x] = src[threadIdx.x];
}

// ---------------------------------------------------------------- bidirectional LSTM layer
// Persistent kernel: 256 blocks (1 per CU). dir = bid>>7; block owns 4 cells
// (c0..c0+3) => 16 gate rows (4 gates x 4 cells). W_ih/W_hh rows live in LDS.
// Per step: x-part GEMM (no recurrent dep, off the critical chain), flag-wait
// for h(t-1), h-part GEMM, reduce, cell update, publish h.
// Publish/consume uses write-through (sc0 sc1) stores + vmcnt(0) + RELAXED
// agent flag stores — NO agent fences (those emit buffer_wbl2/buffer_inv =
// full per-XCD L2 writeback/invalidate per step = 93% of round-1 time).
// Consumer h loads are plain cached loads: L2 is invalidated at dispatch
// start (implicit acquire) and each h(t) line is written exactly once before
// any consumer reads it, so no stale copy can exist — including graph replays.
template<int DIN>
__global__ __launch_bounds__(256) void lstm_bidir(
    const float* __restrict__ x,
    const float* __restrict__ wihF, const float* __restrict__ whhF,
    const float* __restrict__ bihF, const float* __restrict__ bhhF,
    const float* __restrict__ wihR, const float* __restrict__ whhR,
    const float* __restrict__ bihR, const float* __restrict__ bhhR,
    float* __restrict__ hs,          // (B, S, 1024): [0:512]=fwd, [512:1024]=rev
    int* __restrict__ flags)         // 256 ints, flags[bid]
{
    const int tid = threadIdx.x;
    const int bid = blockIdx.x;
    const int dir = bid >> 7;
    const int sub = bid & 127;
    const int c0  = sub << 2;

    const float* wih = dir ? wihR : wihF;
    const float* whh = dir ? whhR : whhF;
    const float* bih = dir ? bihR : bihF;
    const float* bhh = dir ? bhhR : bhhF;

    __shared__ float s_wih[16][DIN + 4];
    __shared__ float s_whh[16][H_ + 4];
    __shared__ float s_stage[16][H_ + 4];
    __shared__ float s_red[4][16][16];
    __shared__ float s_gl[16][17];
    __shared__ float s_bias[16];

    // ---- load weight rows into LDS (once)
    for (int r = 0; r < 16; ++r) {
        const int grow = ((r >> 2) * H_) + c0 + (r & 3);
        const float* srcI = wih + (size_t)grow * DIN;
        for (int i = tid; i < DIN / 4; i += 256)
            *(float4*)&s_wih[r][i * 4] = *(const float4*)&srcI[i * 4];
        const float* srcH = whh + (size_t)grow * H_;
        for (int i = tid; i < H_ / 4; i += 256)
            *(float4*)&s_whh[r][i * 4] = *(const float4*)&srcH[i * 4];
    }
    if (tid < 16) {
        const int grow = ((tid >> 2) * H_) + c0 + (tid & 3);
        s_bias[tid] = bih[grow] + bhh[grow];
    }

    // thread decomposition: tid = ks*16 + (r4*4 + b4)
    const int rb  = tid & 15;
    const int ks  = tid >> 4;
    const int r40 = (rb >> 2) << 2;
    const int b40 = (rb & 3) << 2;
    const int kb  = ks << 5;

    float cstate = 0.0f;                 // meaningful for tid<64
    const int cu_c = tid >> 4;           // cell offset (tid<64)
    const int cu_b = tid & 15;           // batch      (tid<64)

    __syncthreads();

    for (int step = 0; step < S_; ++step) {
        const int t = dir ? (S_ - 1 - step) : step;
        float acc[16];
        #pragma unroll
        for (int a = 0; a < 16; ++a) acc[a] = 0.0f;

        // -------- x part: gates += x_t @ W_ih^T  (no dependency on h)
        #pragma unroll
        for (int half = 0; half < DIN / 512; ++half) {
            __syncthreads();
            for (int i = tid; i < 2048; i += 256) {
                const int bb = i >> 7;
                const int col = (i & 127) << 2;
                *(float4*)&s_stage[bb][col] =
                    *(const float4*)&x[(size_t)(bb * S_ + t) * DIN + half * 512 + col];
            }
            __syncthreads();
            #pragma unroll
            for (int cc = 0; cc < 8; ++cc) {
                const int rot  = ((cc + ks) & 7) << 2;   // bank-conflict rotation
                const int scol = kb + rot;
                const int wcol = half * 512 + scol;
                float4 hv[4], wv[4];
                #pragma unroll
                for (int i = 0; i < 4; ++i) hv[i] = *(const float4*)&s_stage[b40 + i][scol];
                #pragma unroll
                for (int j = 0; j < 4; ++j) wv[j] = *(const float4*)&s_wih[r40 + j][wcol];
                #pragma unroll
                for (int j = 0; j < 4; ++j)
                    #pragma unroll
                    for (int i = 0; i < 4; ++i) {
                        acc[j * 4 + i] = fmaf(wv[j].x, hv[i].x, acc[j * 4 + i]);
                        acc[j * 4 + i] = fmaf(wv[j].y, hv[i].y, acc[j * 4 + i]);
                        acc[j * 4 + i] = fmaf(wv[j].z, hv[i].z, acc[j * 4 + i]);
                        acc[j * 4 + i] = fmaf(wv[j].w, hv[i].w, acc[j * 4 + i]);
                    }
            }
        }

        // -------- wait for h(t-1), then h part: gates += h @ W_hh^T
        if (step > 0) {
            if (tid < 128) {
                int* fp = &flags[dir * 128 + tid];
                while (__hip_atomic_load(fp, __ATOMIC_RELAXED, __HIP_MEMORY_SCOPE_AGENT) < step) { }
            }
            __syncthreads();           // exec + compiler barrier; h lines are fresh
            const int tp = dir ? (t + 1) : (t - 1);
            for (int i = tid; i < 2048; i += 256) {
                const int bb = i >> 7;
                const int col = (i & 127) << 2;
                *(float4*)&s_stage[bb][col] =
                    *(const float4*)&hs[(size_t)(bb * S_ + tp) * 1024 + dir * 512 + col];
            }
            __syncthreads();
            #pragma unroll
            for (int cc = 0; cc < 8; ++cc) {
                const int rot  = ((cc + ks) & 7) << 2;
                const int scol = kb + rot;
                float4 hv[4], wv[4];
                #pragma unroll
                for (int i = 0; i < 4; ++i) hv[i] = *(const float4*)&s_stage[b40 + i][scol];
                #pragma unroll
                for (int j = 0; j < 4; ++j) wv[j] = *(const float4*)&s_whh[r40 + j][scol];
                #pragma unroll
                for (int j = 0; j < 4; ++j)
                    #pragma unroll
                    for (int i = 0; i < 4; ++i) {
                        acc[j * 4 + i] = fmaf(wv[j].x, hv[i].x, acc[j * 4 + i]);
                        acc[j * 4 + i] = fmaf(wv[j].y, hv[i].y, acc[j * 4 + i]);
                        acc[j * 4 + i] = fmaf(wv[j].z, hv[i].z, acc[j * 4 + i]);
                        acc[j * 4 + i] = fmaf(wv[j].w, hv[i].w, acc[j * 4 + i]);
                    }
            }
        }

        // -------- reduce partial sums over the 16 k-slices
        #pragma unroll
        for (int a = 0; a < 16; ++a) {
            float v = acc[a];
            v += __shfl_xor(v, 16);
            v += __shfl_xor(v, 32);
            acc[a] = v;
        }
        if ((tid & 63) < 16) {
            const int w = tid >> 6;
            #pragma unroll
            for (int a = 0; a < 16; ++a) s_red[w][tid & 15][a] = acc[a];
        }
        __syncthreads();
        {
            const int r  = tid >> 4;     // local gate row 0..15
            const int bb = tid & 15;     // batch
            const int rr = ((r >> 2) << 2) + (bb >> 2);
            const int aa = ((r & 3) << 2) + (bb & 3);
            float g = s_bias[r];
            #pragma unroll
            for (int w = 0; w < 4; ++w) g += s_red[w][rr][aa];
            s_gl[r][bb] = g;
        }
        __syncthreads();

        // -------- cell update (wave 0: 4 cells x 16 batches) + publish
        if (tid < 64) {
            const float gi = s_gl[0  + cu_c][cu_b];
            const float gf = s_gl[4  + cu_c][cu_b];
            const float gg = s_gl[8  + cu_c][cu_b];
            const float go = s_gl[12 + cu_c][cu_b];
            const float iv = sigmoidf_(gi);
            const float fv = sigmoidf_(gf);
            const float gv = tanhf(gg);
            const float ov = sigmoidf_(go);
            cstate = fv * cstate + iv * gv;
            const float hval = ov * tanhf(cstate);
            // gather 4 cells of one batch into a vec4 (lane c*16+b holds (c,b))
            f4_t o;
            o.x = hval;                          // lane tid      (cell 0 when tid<16)
            o.y = __shfl(hval, tid + 16);
            o.z = __shfl(hval, tid + 32);
            o.w = __shfl(hval, tid + 48);
            if (tid < 16)
                store_wt4(&hs[(size_t)(tid * S_ + t) * 1024 + dir * 512 + c0], o);
            asm volatile("s_waitcnt vmcnt(0)" ::: "memory");   // h stores acked at LLC
            if (tid == 0)
                __hip_atomic_store(&flags[bid], step + 1,
                                   __ATOMIC_RELAXED, __HIP_MEMORY_SCOPE_AGENT);
        }
    }
}

// ---------------------------------------------------------------- out proj + argmax -> mask
__global__ __launch_bounds__(256) void outproj_kernel(
    const float* __restrict__ x1, const float* __restrict__ out_w,
    const float* __restrict__ out_b, float* __restrict__ res,
    unsigned char* __restrict__ mask)
{
    const int tid  = threadIdx.x;
    const int lane = tid & 63;
    const int w    = tid >> 6;
    const int row  = blockIdx.x * 4 + w;     // b*S + s
    const float* xr = x1 + (size_t)row * 1024;
    float4 xv[4];
    #pragma unroll
    for (int i = 0; i < 4; ++i) xv[i] = *(const float4*)&xr[(i * 64 + lane) << 2];
    float best = -__builtin_inff();
    int bi = 0;
    #pragma unroll
    for (int l = 0; l < L_; ++l) {
        const float* wr = out_w + l * 1024;
        float s = 0.0f;
        #pragma unroll
        for (int i = 0; i < 4; ++i) {
            const float4 wv = *(const float4*)&wr[(i * 64 + lane) << 2];
            s = fmaf(xv[i].x, wv.x, s);
            s = fmaf(xv[i].y, wv.y, s);
            s = fmaf(xv[i].z, wv.z, s);
            s = fmaf(xv[i].w, wv.w, s);
        }
        #pragma unroll
        for (int d = 32; d >= 1; d >>= 1) s += __shfl_xor(s, d);
        s += out_b[l];
        if (lane == l) res[(size_t)row * L_ + l] = s;
        if (s > best) { best = s; bi = l; }     // strict > keeps first index (jnp.argmax)
    }
    if (lane == 0) mask[row] = (unsigned char)(bi != 0);
}

// ---------------------------------------------------------------- batched fp32 GEMM 64x64x16
// MODE 0: C = A @ B^T        (A:(M,K), B:(N,K))      -> scores
// MODE 1: C = A @ B + D      (A:(M,K), B:(K,N))      -> A-out with residual
template<int MODE>
__global__ __launch_bounds__(256) void gemm64(
    const float* __restrict__ A, const float* __restrict__ Bm,
    const float* __restrict__ D, float* __restrict__ C,
    const int M, const int N, const int K)
{
    const int bz = blockIdx.z;
    const float* Ab = A  + (size_t)bz * M * K;
    const float* Bb = Bm + (size_t)bz * N * K;
    const float* Db = (MODE == 1) ? (D + (size_t)bz * M * N) : (const float*)nullptr;
    float* Cb = C + (size_t)bz * M * N;
    const int m0 = blockIdx.y << 6;
    const int n0 = blockIdx.x << 6;
    const int tid = threadIdx.x;
    const int tm = tid >> 4, tn = tid & 15;
    const int am = tid >> 2, ak = (tid & 3) << 2;
    const int bk1 = tid >> 4, bn1 = (tid & 15) << 2;
    __shared__ float As[16][68];
    __shared__ float Bs[16][68];
    float acc[4][4] = {};
    for (int k0 = 0; k0 < K; k0 += 16) {
        const float4 av = *(const float4*)&Ab[(size_t)(m0 + am) * K + k0 + ak];
        float4 bv;
        if (MODE == 0) bv = *(const float4*)&Bb[(size_t)(n0 + am) * K + k0 + ak];
        else           bv = *(const float4*)&Bb[(size_t)(k0 + bk1) * N + n0 + bn1];
        __syncthreads();
        As[ak + 0][am] = av.x; As[ak + 1][am] = av.y;
        As[ak + 2][am] = av.z; As[ak + 3][am] = av.w;
        if (MODE == 0) {
            Bs[ak + 0][am] = bv.x; Bs[ak + 1][am] = bv.y;
            Bs[ak + 2][am] = bv.z; Bs[ak + 3][am] = bv.w;
        } else {
            *(float4*)&Bs[bk1][bn1] = bv;
        }
        __syncthreads();
        #pragma unroll
        for (int k = 0; k < 16; ++k) {
            const float4 a4 = *(const float4*)&As[k][tm << 2];
            const float4 b4 = *(const float4*)&Bs[k][tn << 2];
            acc[0][0] = fmaf(a4.x, b4.x, acc[0][0]); acc[0][1] = fmaf(a4.x, b4.y, acc[0][1]);
            acc[0][2] = fmaf(a4.x, b4.z, acc[0][2]); acc[0][3] = fmaf(a4.x, b4.w, acc[0][3]);
            acc[1][0] = fmaf(a4.y, b4.x, acc[1][0]); acc[1][1] = fmaf(a4.y, b4.y, acc[1][1]);
            acc[1][2] = fmaf(a4.y, b4.z, acc[1][2]); acc[1][3] = fmaf(a4.y, b4.w, acc[1][3]);
            acc[2][0] = fmaf(a4.z, b4.x, acc[2][0]); acc[2][1] = fmaf(a4.z, b4.y, acc[2][1]);
            acc[2][2] = fmaf(a4.z, b4.z, acc[2][2]); acc[2][3] = fmaf(a4.z, b4.w, acc[2][3]);
            acc[3][0] = fmaf(a4.w, b4.x, acc[3][0]); acc[3][1] = fmaf(a4.w, b4.y, acc[3][1]);
            acc[3][2] = fmaf(a4.w, b4.z, acc[3][2]); acc[3][3] = fmaf(a4.w, b4.w, acc[3][3]);
        }
    }
    #pragma unroll
    for (int j = 0; j < 4; ++j) {
        const size_t ci = (size_t)(m0 + (tm << 2) + j) * N + n0 + (tn << 2);
        float4 o = make_float4(acc[j][0], acc[j][1], acc[j][2], acc[j][3]);
        if (MODE == 1) {
            const float4 dv = *(const float4*)&Db[ci];
            o.x += dv.x; o.y += dv.y; o.z += dv.z; o.w += dv.w;
        }
        *(float4*)&Cb[ci] = o;
    }
}

// ---------------------------------------------------------------- dual masked softmax (in place)
__global__ __launch_bounds__(256) void softmax_kernel(float* __restrict__ sc,
                                                      const unsigned char* __restrict__ mask)
{
    const float INF = __builtin_inff();
    const int row = blockIdx.x;          // b*S + s
    const int b = row >> 10;
    float* pr = sc + (size_t)row * 1024;
    const unsigned char* mr = mask + b * 1024;
    const int tid = threadIdx.x;
    const int lane = tid & 63;
    const int w = tid >> 6;
    const int j0 = tid << 2;
    const float4 v = *(const float4*)&pr[j0];
    const unsigned mu = *(const unsigned*)&mr[j0];
    const bool m0 = (mu & 0xffu) != 0, m1 = ((mu >> 8) & 0xffu) != 0;
    const bool m2 = ((mu >> 16) & 0xffu) != 0, m3 = ((mu >> 24) & 0xffu) != 0;

    float mme = -INF, mot = -INF;
    if (m0) mme = fmaxf(mme, v.x); else mot = fmaxf(mot, v.x);
    if (m1) mme = fmaxf(mme, v.y); else mot = fmaxf(mot, v.y);
    if (m2) mme = fmaxf(mme, v.z); else mot = fmaxf(mot, v.z);
    if (m3) mme = fmaxf(mme, v.w); else mot = fmaxf(mot, v.w);
    #pragma unroll
    for (int d = 32; d >= 1; d >>= 1) {
        mme = fmaxf(mme, __shfl_xor(mme, d));
        mot = fmaxf(mot, __shfl_xor(mot, d));
    }
    __shared__ float sm[2][4];
    if (lane == 0) { sm[0][w] = mme; sm[1][w] = mot; }
    __syncthreads();
    float Mme = fmaxf(fmaxf(sm[0][0], sm[0][1]), fmaxf(sm[0][2], sm[0][3]));
    float Mot = fmaxf(fmaxf(sm[1][0], sm[1][1]), fmaxf(sm[1][2], sm[1][3]));
    const float MmeU = (Mme == -INF) ? 0.0f : Mme;
    const float MotU = (Mot == -INF) ? 0.0f : Mot;

    const float e0 = expf(v.x - (m0 ? MmeU : MotU));
    const float e1 = expf(v.y - (m1 ? MmeU : MotU));
    const float e2 = expf(v.z - (m2 ? MmeU : MotU));
    const float e3 = expf(v.w - (m3 ? MmeU : MotU));
    float sme = 0.0f, sot = 0.0f;
    if (m0) sme += e0; else sot += e0;
    if (m1) sme += e1; else sot += e1;
    if (m2) sme += e2; else sot += e2;
    if (m3) sme += e3; else sot += e3;
    #pragma unroll
    for (int d = 32; d >= 1; d >>= 1) {
        sme += __shfl_xor(sme, d);
        sot += __shfl_xor(sot, d);
    }
    __syncthreads();
    if (lane == 0) { sm[0][w] = sme; sm[1][w] = sot; }
    __syncthreads();
    const float Dme = sm[0][0] + sm[0][1] + sm[0][2] + sm[0][3];
    const float Dot = sm[1][0] + sm[1][1] + sm[1][2] + sm[1][3];

    float4 o;
    o.x = m0 ? (Dme > 0.0f ? e0 / Dme : 0.0f) : (Dot > 0.0f ? e0 / Dot : 0.0f);
    o.y = m1 ? (Dme > 0.0f ? e1 / Dme : 0.0f) : (Dot > 0.0f ? e1 / Dot : 0.0f);
    o.z = m2 ? (Dme > 0.0f ? e2 / Dme : 0.0f) : (Dot > 0.0f ? e2 / Dot : 0.0f);
    o.w = m3 ? (Dme > 0.0f ? e3 / Dme : 0.0f) : (Dot > 0.0f ? e3 / Dot : 0.0f);
    *(float4*)&pr[j0] = o;
}

// ---------------------------------------------------------------- launch
extern "C" void kernel_launch(void* const* d_in, const int* in_sizes, int n_in,
                              void* d_out, int out_size, void* d_ws, size_t ws_size,
                              hipStream_t stream)
{
    const float* emb     = (const float*)d_in[0];
    const float* wih_l0  = (const float*)d_in[1];
    const float* whh_l0  = (const float*)d_in[2];
    const float* bih_l0  = (const float*)d_in[3];
    const float* bhh_l0  = (const float*)d_in[4];
    const float* wih_l0r = (const float*)d_in[5];
    const float* whh_l0r = (const float*)d_in[6];
    const float* bih_l0r = (const float*)d_in[7];
    const float* bhh_l0r = (const float*)d_in[8];
    const float* wih_l1  = (const float*)d_in[9];
    const float* whh_l1  = (const float*)d_in[10];
    const float* bih_l1  = (const float*)d_in[11];
    const float* bhh_l1  = (const float*)d_in[12];
    const float* wih_l1r = (const float*)d_in[13];
    const float* whh_l1r = (const float*)d_in[14];
    const float* bih_l1r = (const float*)d_in[15];
    const float* bhh_l1r = (const float*)d_in[16];
    const float* out_w   = (const float*)d_in[17];
    const float* out_b   = (const float*)d_in[18];
    const int*   tokens  = (const int*)d_in[19];

    float* out     = (float*)d_out;
    float* A_out   = out;                          // (16,1024,1024)
    float* res_out = out + 16777216;               // (16,1024,10)

    float* ws = (float*)d_ws;
    float* x0 = ws;                                //  8,388,608 f
    float* h0 = ws + 8388608;                      // 16,777,216 f
    float* x1 = h0 + 16777216;                     // 16,777,216 f
    float* sc = x1 + 16777216;                     // 16,777,216 f (scores, then P in place)
    unsigned char* mask = (unsigned char*)(sc + 16777216);   // 16,384 B
    int* flags0 = (int*)(mask + 16384);            // 256 ints
    int* flags1 = flags0 + 256;

    (void)in_sizes; (void)n_in; (void)out_size; (void)ws_size;

    (void)hipMemsetAsync(flags0, 0, 512 * sizeof(int), stream);

    embed_kernel<<<B_ * S_, 128, 0, stream>>>(tokens, emb, x0);

    lstm_bidir<512><<<256, 256, 0, stream>>>(
        x0, wih_l0, whh_l0, bih_l0, bhh_l0,
        wih_l0r, whh_l0r, bih_l0r, bhh_l0r, h0, flags0);

    lstm_bidir<1024><<<256, 256, 0, stream>>>(
        h0, wih_l1, whh_l1, bih_l1, bhh_l1,
        wih_l1r, whh_l1r, bih_l1r, bhh_l1r, x1, flags1);

    outproj_kernel<<<(B_ * S_) / 4, 256, 0, stream>>>(x1, out_w, out_b, res_out, mask);

    dim3 gg(16, 16, 16);
    gemm64<0><<<gg, 256, 0, stream>>>(x1, x1, nullptr, sc, 1024, 1024, 1024);

    softmax_kernel<<<B_ * S_, 256, 0, stream>>>(sc, mask);

    gemm64<1><<<gg, 256, 0, stream>>>(sc, x1, x1, A_out, 1024, 1024, 1024);
}